// Round 4
// baseline (3910.756 us; speedup 1.0000x reference)
//
#include <hip/hip_runtime.h>
#include <hip/hip_bf16.h>

typedef __hip_bfloat16 bf16;

#define Bn 4
#define Cn 256
#define C2n 512
#define Hn 128
#define Wn 128
#define HWn 16384
#define HEADSn 8
#define CHn 32
#define OCB 8
#define STRIP 8

static __device__ __forceinline__ float b2f(bf16 v) { return __bfloat162float(v); }
static __device__ __forceinline__ bf16 f2b(float v) { return __float2bfloat16(v); }

// ---------------- LayerNorm over channel dim (per pixel) ----------------
// reads f32, writes bf16 (and optional exact f32 copy for the residual)
__global__ void ln_kernel(const float* __restrict__ x,
                          const float* __restrict__ gw,
                          const float* __restrict__ gb,
                          bf16* __restrict__ o16,
                          float* __restrict__ o32) {
    __shared__ float sw[Cn], sb[Cn];
    int tid = threadIdx.x;
    if (tid < Cn) { sw[tid] = gw[tid]; sb[tid] = gb[tid]; }
    __syncthreads();
    int pix = blockIdx.x * 256 + tid;          // 0 .. B*HW-1
    int b = pix >> 14;
    int hw = pix & (HWn - 1);
    const float* xb = x + (size_t)b * Cn * HWn + hw;
    float s = 0.f, ss = 0.f;
    for (int c = 0; c < Cn; c++) {
        float v = xb[(size_t)c * HWn];
        s += v; ss += v * v;
    }
    float mu  = s * (1.f / Cn);
    float var = ss * (1.f / Cn) - mu * mu;
    float inv = rsqrtf(var + 1e-5f);
    bf16* ob = o16 + (size_t)b * Cn * HWn + hw;
    float* ob32 = o32 ? o32 + (size_t)b * Cn * HWn + hw : nullptr;
    for (int c = 0; c < Cn; c++) {
        float v = (xb[(size_t)c * HWn] - mu) * inv * sw[c] + sb[c];
        ob[(size_t)c * HWn] = f2b(v);
        if (ob32) ob32[(size_t)c * HWn] = v;
    }
}

// ---------------- fused kv = dw3x3( conv1x1(xn) ) ----------------
// Block: 8 output channels x 8-row strip; 5 halo pixels/thread in registers.
__global__ void fused_kv_kernel(const bf16* __restrict__ xn,
                                const float* __restrict__ Wkv,
                                const float* __restrict__ Wdw,
                                bf16* __restrict__ kvdw) {
    __shared__ float wT[Cn][OCB];               // 8 KB
    __shared__ float wd[OCB][9];
    __shared__ float stage[(STRIP + 2) * Wn];   // 1280 floats
    int tid = threadIdx.x;
    int r0  = blockIdx.x * STRIP;
    int oc0 = blockIdx.y * OCB;
    int b   = blockIdx.z;
    for (int i = tid; i < Cn * OCB; i += 256) {
        int j = i & (OCB - 1);
        int c = i >> 3;
        wT[c][j] = Wkv[(size_t)(oc0 + j) * Cn + c];
    }
    if (tid < OCB * 9) {
        int j = tid / 9, t = tid % 9;
        wd[j][t] = Wdw[(oc0 + j) * 9 + t];
    }
    __syncthreads();

    float acc[5][OCB];
    #pragma unroll
    for (int k = 0; k < 5; k++)
        #pragma unroll
        for (int j = 0; j < OCB; j++) acc[k][j] = 0.f;

    int rr[5], col[5]; bool ok[5];
    #pragma unroll
    for (int k = 0; k < 5; k++) {
        int p = tid + k * 256;          // 0..1279
        rr[k]  = r0 - 1 + (p >> 7);     // halo row
        col[k] = p & 127;
        ok[k]  = (rr[k] >= 0 && rr[k] < Hn);
    }
    const bf16* xb = xn + (size_t)b * Cn * HWn;
    for (int c = 0; c < Cn; c++) {
        float v[5];
        #pragma unroll
        for (int k = 0; k < 5; k++)
            v[k] = ok[k] ? b2f(xb[(size_t)c * HWn + rr[k] * Wn + col[k]]) : 0.f;
        #pragma unroll
        for (int k = 0; k < 5; k++)
            #pragma unroll
            for (int j = 0; j < OCB; j++) acc[k][j] += wT[c][j] * v[k];
    }

    for (int j = 0; j < OCB; j++) {
        __syncthreads();
        #pragma unroll
        for (int k = 0; k < 5; k++) stage[tid + k * 256] = acc[k][j];
        __syncthreads();
        #pragma unroll
        for (int k = 0; k < 4; k++) {
            int q  = tid + k * 256;     // output pixel in strip
            int ry = q >> 7;            // 0..7
            int cl = q & 127;
            float s = 0.f;
            #pragma unroll
            for (int dy = 0; dy < 3; dy++) {
                #pragma unroll
                for (int dx = 0; dx < 3; dx++) {
                    int cc = cl + dx - 1;
                    if (cc >= 0 && cc < Wn)
                        s += wd[j][dy * 3 + dx] * stage[(ry + dy) * Wn + cc];
                }
            }
            kvdw[((size_t)b * C2n + oc0 + j) * HWn + (r0 + ry) * Wn + cl] = f2b(s);
        }
    }
}

// ---------------- q conv: 3x3 SAME, 256->256 ----------------
__global__ void qconv_kernel(const bf16* __restrict__ yn,
                             const float* __restrict__ Wq,
                             bf16* __restrict__ q) {
    __shared__ float wlds[64][9][OCB];  // 18432 B
    int tid = threadIdx.x;
    int oc0 = blockIdx.y * OCB;
    int b   = blockIdx.z;
    int hw  = blockIdx.x * 256 + tid;
    int y0 = hw >> 7, x0 = hw & 127;
    float acc[OCB] = {0.f, 0.f, 0.f, 0.f, 0.f, 0.f, 0.f, 0.f};
    for (int cc = 0; cc < Cn; cc += 64) {
        __syncthreads();
        for (int i = tid; i < 64 * 9 * OCB; i += 256) {
            int j = i & (OCB - 1);
            int t = (i >> 3) % 9;
            int c = i / 72;
            wlds[c][t][j] = Wq[((size_t)(oc0 + j) * Cn + cc + c) * 9 + t];
        }
        __syncthreads();
        const bf16* ybase = yn + ((size_t)b * Cn + cc) * HWn;
        for (int c = 0; c < 64; c++) {
            float a[9];
            #pragma unroll
            for (int dy = 0; dy < 3; dy++) {
                int yy = y0 + dy - 1;
                #pragma unroll
                for (int dx = 0; dx < 3; dx++) {
                    int xx = x0 + dx - 1;
                    bool okp = (yy >= 0 && yy < Hn && xx >= 0 && xx < Wn);
                    a[dy * 3 + dx] = okp ? b2f(ybase[(size_t)c * HWn + yy * Wn + xx]) : 0.f;
                }
            }
            #pragma unroll
            for (int t = 0; t < 9; t++) {
                float av = a[t];
                #pragma unroll
                for (int j = 0; j < OCB; j++) acc[j] += wlds[c][t][j] * av;
            }
        }
    }
    #pragma unroll
    for (int j = 0; j < OCB; j++)
        q[((size_t)b * Cn + oc0 + j) * HWn + hw] = f2b(acc[j]);
}

// ---------------- per-row rsqrt(sumsq) scales for q and k ----------------
__global__ void norm_kernel(const bf16* __restrict__ q,
                            const bf16* __restrict__ kvdw,
                            float* __restrict__ qs,
                            float* __restrict__ ks) {
    int row = blockIdx.x;          // 0..1023 : b*256 + channel
    int b = row >> 8, c = row & 255;
    int tid = threadIdx.x;
    const bf16* src = (blockIdx.y == 0)
        ? q    + ((size_t)b * Cn  + c) * HWn
        : kvdw + ((size_t)b * C2n + c) * HWn;   // k = first 256 channels of kvdw
    float ssum = 0.f;
    for (int i = tid; i < HWn; i += 256) {
        float v = b2f(src[i]);
        ssum += v * v;
    }
    __shared__ float red[256];
    red[tid] = ssum; __syncthreads();
    if (tid < 128) red[tid] += red[tid + 128];
    __syncthreads();
    if (tid < 64) red[tid] += red[tid + 64];
    __syncthreads();
    if (tid < 32) {
        float v = red[tid] + red[tid + 32];
        for (int off = 16; off > 0; off >>= 1) v += __shfl_xor(v, off);
        if (tid == 0) {
            float* dst = (blockIdx.y == 0) ? qs : ks;
            dst[row] = 1.f / fmaxf(sqrtf(v), 1e-12f);
        }
    }
}

// ---------------- attn logits + softmax: one block per (bh, c-row) ----------------
__global__ void attn_kernel(const bf16* __restrict__ q,
                            const bf16* __restrict__ kvdw,
                            const float* __restrict__ qs,
                            const float* __restrict__ ks,
                            const float* __restrict__ temp,
                            float* __restrict__ attn) {
    int c  = blockIdx.x;   // 0..31 (within head)
    int bh = blockIdx.y;   // 0..31
    int b = bh >> 3, h = bh & 7;
    int tid = threadIdx.x;
    int d = tid & 31, s = tid >> 5;
    const bf16* qrow  = q    + ((size_t)b * Cn + h * CHn + c) * HWn;
    const bf16* kbase = kvdw + ((size_t)b * C2n + h * CHn) * HWn;
    __shared__ float kt[32][129];
    __shared__ float qt[128];
    __shared__ float red[256];
    float acc = 0.f;
    for (int t0 = 0; t0 < HWn; t0 += 128) {
        __syncthreads();
        if (tid < 128) qt[tid] = b2f(qrow[t0 + tid]);
        for (int i = tid; i < 32 * 128; i += 256) {
            int dd = i >> 7, nn = i & 127;
            kt[dd][nn] = b2f(kbase[(size_t)dd * HWn + t0 + nn]);
        }
        __syncthreads();
        #pragma unroll
        for (int i = 0; i < 16; i++) {
            int nn = s * 16 + i;
            acc += qt[nn] * kt[d][nn];
        }
    }
    red[tid] = acc; __syncthreads();
    if (tid < 128) red[tid] += red[tid + 128];
    __syncthreads();
    if (tid < 64) red[tid] += red[tid + 64];
    __syncthreads();
    if (tid < 32) {
        float v = red[tid] + red[tid + 32];
        v *= qs[b * Cn + h * CHn + c] * ks[b * Cn + h * CHn + tid] * temp[h];
        float m = v;
        for (int off = 16; off > 0; off >>= 1) m = fmaxf(m, __shfl_xor(m, off));
        float e = __expf(v - m);
        float ssum = e;
        for (int off = 16; off > 0; off >>= 1) ssum += __shfl_xor(ssum, off);
        attn[((size_t)bh * 32 + c) * 32 + tid] = e / ssum;
    }
}

// ---------------- out = attn @ v ----------------
__global__ void av_kernel(const float* __restrict__ attn,
                          const bf16* __restrict__ kvdw,
                          bf16* __restrict__ out) {
    int bh = blockIdx.y;
    int b = bh >> 3, h = bh & 7;
    int tid = threadIdx.x;
    int n = blockIdx.x * 256 + tid;
    __shared__ float At[32][32];   // At[d][c]
    for (int i = tid; i < 1024; i += 256) {
        int cc = i >> 5, dd = i & 31;
        At[dd][cc] = attn[((size_t)bh * 32 + cc) * 32 + dd];
    }
    __syncthreads();
    const bf16* vbase = kvdw + ((size_t)b * C2n + Cn + h * CHn) * HWn;  // v = second half
    float acc[32];
    #pragma unroll
    for (int c = 0; c < 32; c++) acc[c] = 0.f;
    for (int d = 0; d < 32; d++) {
        float vv = b2f(vbase[(size_t)d * HWn + n]);
        #pragma unroll
        for (int c = 0; c < 32; c++) acc[c] += At[d][c] * vv;
    }
    bf16* obase = out + ((size_t)b * Cn + h * CHn) * HWn + n;
    #pragma unroll
    for (int c = 0; c < 32; c++) obase[(size_t)c * HWn] = f2b(acc[c]);
}

// ---------------- proj 1x1 + residual (writes final f32 output) ----------------
__global__ void proj_kernel(const bf16* __restrict__ ao,
                            const float* __restrict__ Wp,
                            const float* __restrict__ yn32,
                            float* __restrict__ out) {
    __shared__ float wT[Cn][OCB];
    int tid = threadIdx.x;
    int oc0 = blockIdx.y * OCB;
    int b   = blockIdx.z;
    for (int i = tid; i < Cn * OCB; i += 256) {
        int j = i & (OCB - 1);
        int c = i >> 3;
        wT[c][j] = Wp[(size_t)(oc0 + j) * Cn + c];
    }
    __syncthreads();
    int hw = blockIdx.x * 256 + tid;
    const bf16* ab = ao + (size_t)b * Cn * HWn + hw;
    float acc[OCB] = {0.f, 0.f, 0.f, 0.f, 0.f, 0.f, 0.f, 0.f};
    for (int c = 0; c < Cn; c++) {
        float v = b2f(ab[(size_t)c * HWn]);
        #pragma unroll
        for (int j = 0; j < OCB; j++) acc[j] += wT[c][j] * v;
    }
    #pragma unroll
    for (int j = 0; j < OCB; j++) {
        size_t idx = ((size_t)b * Cn + oc0 + j) * HWn + hw;
        out[idx] = yn32[idx] + acc[j];
    }
}

extern "C" void kernel_launch(void* const* d_in, const int* in_sizes, int n_in,
                              void* d_out, int out_size, void* d_ws, size_t ws_size,
                              hipStream_t stream) {
    const float* x     = (const float*)d_in[0];
    const float* y     = (const float*)d_in[1];
    const float* lnkw  = (const float*)d_in[2];
    const float* lnkb  = (const float*)d_in[3];
    const float* lnqw  = (const float*)d_in[4];
    const float* lnqb  = (const float*)d_in[5];
    const float* Wkv   = (const float*)d_in[6];
    const float* Wdw   = (const float*)d_in[7];
    const float* Wq    = (const float*)d_in[8];
    const float* Wproj = (const float*)d_in[9];
    const float* temp  = (const float*)d_in[10];
    float* out = (float*)d_out;

    char* ws = (char*)d_ws;
    const size_t TEN = (size_t)Bn * Cn * HWn;          // 16,777,216 elems
    bf16*  bufA = (bf16*)(ws);                         // 32 MB: xn -> q -> ao
    bf16*  bufB = (bf16*)(ws + TEN * 2);               // 32 MB: yn (bf16)
    bf16*  kvdw = (bf16*)(ws + TEN * 4);               // 64 MB
    float* yn32 = (float*)(ws + TEN * 8);              // 64 MB: yn (f32, residual)
    char*  wp   = ws + TEN * 12;
    float* qs    = (float*)(wp);          wp += 4096;
    float* ksr   = (float*)(wp);          wp += 4096;
    float* attnP = (float*)(wp);          wp += 131072;   // total ~192 MB

    // 1-2. LayerNorms
    ln_kernel<<<dim3(Bn * HWn / 256), 256, 0, stream>>>(x, lnkw, lnkb, bufA, nullptr); // xn
    ln_kernel<<<dim3(Bn * HWn / 256), 256, 0, stream>>>(y, lnqw, lnqb, bufB, yn32);    // yn
    // 3. fused kv: dw3x3(conv1x1(xn)) -> kvdw
    fused_kv_kernel<<<dim3(Hn / STRIP, C2n / OCB, Bn), 256, 0, stream>>>(bufA, Wkv, Wdw, kvdw);
    // 4. q = 3x3 conv -> bufA (xn dead after fused_kv)
    qconv_kernel<<<dim3(HWn / 256, Cn / OCB, Bn), 256, 0, stream>>>(bufB, Wq, bufA);
    // 5. L2-norm scales for q and k
    norm_kernel<<<dim3(Bn * Cn, 2), 256, 0, stream>>>(bufA, kvdw, qs, ksr);
    // 6. attention logits + softmax
    attn_kernel<<<dim3(CHn, Bn * HEADSn), 256, 0, stream>>>(bufA, kvdw, qs, ksr, temp, attnP);
    // 7. attn @ v -> bufA (q dead after attn)
    av_kernel<<<dim3(HWn / 256, Bn * HEADSn), 256, 0, stream>>>(attnP, kvdw, bufA);
    // 8. proj 1x1 + residual -> final f32 output
    proj_kernel<<<dim3(HWn / 256, Cn / OCB, Bn), 256, 0, stream>>>(bufA, Wproj, yn32, out);
}

// Round 5
// 2145.856 us; speedup vs baseline: 1.8225x; 1.8225x over previous
//
#include <hip/hip_runtime.h>
#include <hip/hip_bf16.h>

typedef __hip_bfloat16 bf16;
typedef __attribute__((ext_vector_type(8))) short bf16x8;
typedef __attribute__((ext_vector_type(4))) float f32x4;

#define Bn 4
#define Cn 256
#define C2n 512
#define Hn 128
#define Wn 128
#define HWn 16384
#define HEADSn 8
#define CHn 32
#define OCB 8
#define STRIP 8
#define LDP 40   // 32 + 8 pad (16B-aligned rows, 2-way banks = free)

static __device__ __forceinline__ float b2f(bf16 v) { return __bfloat162float(v); }
static __device__ __forceinline__ bf16 f2b(float v) { return __float2bfloat16(v); }

// ---------------- LayerNorm over channel dim (per pixel) ----------------
__global__ void ln_kernel(const float* __restrict__ x,
                          const float* __restrict__ gw,
                          const float* __restrict__ gb,
                          bf16* __restrict__ o16,
                          float* __restrict__ o32) {
    __shared__ float sw[Cn], sb[Cn];
    int tid = threadIdx.x;
    if (tid < Cn) { sw[tid] = gw[tid]; sb[tid] = gb[tid]; }
    __syncthreads();
    int pix = blockIdx.x * 256 + tid;          // 0 .. B*HW-1
    int b = pix >> 14;
    int hw = pix & (HWn - 1);
    const float* xb = x + (size_t)b * Cn * HWn + hw;
    float s = 0.f, ss = 0.f;
    for (int c = 0; c < Cn; c++) {
        float v = xb[(size_t)c * HWn];
        s += v; ss += v * v;
    }
    float mu  = s * (1.f / Cn);
    float var = ss * (1.f / Cn) - mu * mu;
    float inv = rsqrtf(var + 1e-5f);
    bf16* ob = o16 + (size_t)b * Cn * HWn + hw;
    float* ob32 = o32 ? o32 + (size_t)b * Cn * HWn + hw : nullptr;
    for (int c = 0; c < Cn; c++) {
        float v = (xb[(size_t)c * HWn] - mu) * inv * sw[c] + sb[c];
        ob[(size_t)c * HWn] = f2b(v);
        if (ob32) ob32[(size_t)c * HWn] = v;
    }
}

// ---------------- repack Wq: f32 [oc][c][3][3] -> bf16 [tap][oc][c] ----------------
__global__ void wq_repack_kernel(const float* __restrict__ Wq, bf16* __restrict__ wp) {
    int i = blockIdx.x * 256 + threadIdx.x;     // over oc*c = 65536
    if (i < Cn * Cn) {
        #pragma unroll
        for (int t = 0; t < 9; t++)
            wp[(size_t)t * Cn * Cn + i] = f2b(Wq[(size_t)i * 9 + t]);
    }
}

// ---------------- transpose: [b][c][hw] bf16 -> [b][hw][c] bf16 ----------------
__global__ void transpose_kernel(const bf16* __restrict__ src, bf16* __restrict__ dst) {
    __shared__ unsigned int t[64][65];   // u32 slots: conflict-light both phases
    int tid = threadIdx.x;
    int pxt = blockIdx.x;   // 0..255
    int ct  = blockIdx.y;   // 0..3
    int b   = blockIdx.z;
    const bf16* sb = src + ((size_t)b * Cn + ct * 64) * HWn + pxt * 64;
    for (int i = tid; i < 512; i += 256) {
        int r = i >> 3, sg = (i & 7) * 8;            // r = c row, sg = px seg
        bf16x8 v = *(const bf16x8*)&sb[(size_t)r * HWn + sg];
        #pragma unroll
        for (int j = 0; j < 8; j++) t[r][sg + j] = (unsigned int)(unsigned short)v[j];
    }
    __syncthreads();
    bf16* db = dst + ((size_t)b * HWn + pxt * 64) * Cn + ct * 64;
    for (int i = tid; i < 512; i += 256) {
        int r = i >> 3, sg = (i & 7) * 8;            // r = px row, sg = c seg
        bf16x8 v;
        #pragma unroll
        for (int j = 0; j < 8; j++) v[j] = (short)(unsigned short)t[sg + j][r];
        *(bf16x8*)&db[(size_t)r * Cn + sg] = v;
    }
}

// ---------------- q conv 3x3 as implicit GEMM via MFMA ----------------
// D[oc][px] = sum over (c,tap) Wq[oc][c,tap] * yn[c][y+dy][px+dx]
// Block: 128 oc x 128 px (one image row). 4 waves x (2m x 8n) 16x16x32 tiles.
__global__ __launch_bounds__(256) void qconv_mfma_kernel(
        const bf16* __restrict__ yn_pm,    // [b][px][c]
        const bf16* __restrict__ wq_pk,    // [tap][oc][c]
        bf16* __restrict__ q) {            // [b][oc][px]
    __shared__ short Als[128 * LDP];
    __shared__ short Bls[128 * LDP];
    int tid  = threadIdx.x;
    int y    = blockIdx.x;
    int oc0  = blockIdx.y * 128;
    int b    = blockIdx.z;
    int wave = tid >> 6, lane = tid & 63;
    int lm = lane & 15, kq = lane >> 4;
    int k0 = kq * 8;

    f32x4 acc[2][8];
    #pragma unroll
    for (int mt = 0; mt < 2; mt++)
        #pragma unroll
        for (int nt = 0; nt < 8; nt++) acc[mt][nt] = (f32x4){0.f, 0.f, 0.f, 0.f};

    const short* ypb = (const short*)(yn_pm + (size_t)b * HWn * Cn);

    for (int tap = 0; tap < 9; tap++) {
        int dy = tap / 3 - 1, dx = tap % 3 - 1;
        int yy = y + dy;
        if (yy < 0 || yy >= Hn) continue;
        const short* wtap  = (const short*)(wq_pk + (size_t)tap * Cn * Cn);
        const short* ybase = ypb + (size_t)yy * Wn * Cn;
        for (int kc = 0; kc < Cn; kc += 32) {
            __syncthreads();
            for (int i = tid; i < 512; i += 256) {
                int r = i >> 2, sg = (i & 3) * 8;
                *(bf16x8*)&Als[r * LDP + sg] =
                    *(const bf16x8*)&wtap[(size_t)(oc0 + r) * Cn + kc + sg];
                int xs = r + dx;
                bf16x8 v = {0, 0, 0, 0, 0, 0, 0, 0};
                if (xs >= 0 && xs < Wn)
                    v = *(const bf16x8*)&ybase[(size_t)xs * Cn + kc + sg];
                *(bf16x8*)&Bls[r * LDP + sg] = v;
            }
            __syncthreads();
            bf16x8 afr[2], bfr[8];
            #pragma unroll
            for (int mt = 0; mt < 2; mt++)
                afr[mt] = *(const bf16x8*)&Als[(wave * 32 + mt * 16 + lm) * LDP + k0];
            #pragma unroll
            for (int nt = 0; nt < 8; nt++)
                bfr[nt] = *(const bf16x8*)&Bls[(nt * 16 + lm) * LDP + k0];
            #pragma unroll
            for (int mt = 0; mt < 2; mt++)
                #pragma unroll
                for (int nt = 0; nt < 8; nt++)
                    acc[mt][nt] = __builtin_amdgcn_mfma_f32_16x16x32_bf16(
                        afr[mt], bfr[nt], acc[mt][nt], 0, 0, 0);
        }
    }
    bf16* qb = q + ((size_t)b * Cn + oc0) * HWn + (size_t)y * Wn;
    #pragma unroll
    for (int mt = 0; mt < 2; mt++) {
        int ocl = wave * 32 + mt * 16 + kq * 4;
        #pragma unroll
        for (int nt = 0; nt < 8; nt++) {
            int px = nt * 16 + lm;
            #pragma unroll
            for (int r = 0; r < 4; r++)
                qb[(size_t)(ocl + r) * HWn + px] = f2b(acc[mt][nt][r]);
        }
    }
}

// ---------------- fused kv = dw3x3( conv1x1(xn) ) ----------------
__global__ void fused_kv_kernel(const bf16* __restrict__ xn,
                                const float* __restrict__ Wkv,
                                const float* __restrict__ Wdw,
                                bf16* __restrict__ kvdw) {
    __shared__ float wT[Cn][OCB];
    __shared__ float wd[OCB][9];
    __shared__ float stage[(STRIP + 2) * Wn];
    int tid = threadIdx.x;
    int r0  = blockIdx.x * STRIP;
    int oc0 = blockIdx.y * OCB;
    int b   = blockIdx.z;
    for (int i = tid; i < Cn * OCB; i += 256) {
        int j = i & (OCB - 1);
        int c = i >> 3;
        wT[c][j] = Wkv[(size_t)(oc0 + j) * Cn + c];
    }
    if (tid < OCB * 9) {
        int j = tid / 9, t = tid % 9;
        wd[j][t] = Wdw[(oc0 + j) * 9 + t];
    }
    __syncthreads();

    float acc[5][OCB];
    #pragma unroll
    for (int k = 0; k < 5; k++)
        #pragma unroll
        for (int j = 0; j < OCB; j++) acc[k][j] = 0.f;

    int rr[5], col[5]; bool ok[5];
    #pragma unroll
    for (int k = 0; k < 5; k++) {
        int p = tid + k * 256;
        rr[k]  = r0 - 1 + (p >> 7);
        col[k] = p & 127;
        ok[k]  = (rr[k] >= 0 && rr[k] < Hn);
    }
    const bf16* xb = xn + (size_t)b * Cn * HWn;
    for (int c = 0; c < Cn; c++) {
        float v[5];
        #pragma unroll
        for (int k = 0; k < 5; k++)
            v[k] = ok[k] ? b2f(xb[(size_t)c * HWn + rr[k] * Wn + col[k]]) : 0.f;
        #pragma unroll
        for (int k = 0; k < 5; k++)
            #pragma unroll
            for (int j = 0; j < OCB; j++) acc[k][j] += wT[c][j] * v[k];
    }

    for (int j = 0; j < OCB; j++) {
        __syncthreads();
        #pragma unroll
        for (int k = 0; k < 5; k++) stage[tid + k * 256] = acc[k][j];
        __syncthreads();
        #pragma unroll
        for (int k = 0; k < 4; k++) {
            int q  = tid + k * 256;
            int ry = q >> 7;
            int cl = q & 127;
            float s = 0.f;
            #pragma unroll
            for (int dy = 0; dy < 3; dy++) {
                #pragma unroll
                for (int dx = 0; dx < 3; dx++) {
                    int cc = cl + dx - 1;
                    if (cc >= 0 && cc < Wn)
                        s += wd[j][dy * 3 + dx] * stage[(ry + dy) * Wn + cc];
                }
            }
            kvdw[((size_t)b * C2n + oc0 + j) * HWn + (r0 + ry) * Wn + cl] = f2b(s);
        }
    }
}

// ---------------- per-row rsqrt(sumsq) scales for q and k ----------------
__global__ void norm_kernel(const bf16* __restrict__ q,
                            const bf16* __restrict__ kvdw,
                            float* __restrict__ qs,
                            float* __restrict__ ks) {
    int row = blockIdx.x;
    int b = row >> 8, c = row & 255;
    int tid = threadIdx.x;
    const bf16* src = (blockIdx.y == 0)
        ? q    + ((size_t)b * Cn  + c) * HWn
        : kvdw + ((size_t)b * C2n + c) * HWn;
    float ssum = 0.f;
    for (int i = tid; i < HWn; i += 256) {
        float v = b2f(src[i]);
        ssum += v * v;
    }
    __shared__ float red[256];
    red[tid] = ssum; __syncthreads();
    if (tid < 128) red[tid] += red[tid + 128];
    __syncthreads();
    if (tid < 64) red[tid] += red[tid + 64];
    __syncthreads();
    if (tid < 32) {
        float v = red[tid] + red[tid + 32];
        for (int off = 16; off > 0; off >>= 1) v += __shfl_xor(v, off);
        if (tid == 0) {
            float* dst = (blockIdx.y == 0) ? qs : ks;
            dst[row] = 1.f / fmaxf(sqrtf(v), 1e-12f);
        }
    }
}

// ---------------- attn logits + softmax ----------------
__global__ void attn_kernel(const bf16* __restrict__ q,
                            const bf16* __restrict__ kvdw,
                            const float* __restrict__ qs,
                            const float* __restrict__ ks,
                            const float* __restrict__ temp,
                            float* __restrict__ attn) {
    int c  = blockIdx.x;
    int bh = blockIdx.y;
    int b = bh >> 3, h = bh & 7;
    int tid = threadIdx.x;
    int d = tid & 31, s = tid >> 5;
    const bf16* qrow  = q    + ((size_t)b * Cn + h * CHn + c) * HWn;
    const bf16* kbase = kvdw + ((size_t)b * C2n + h * CHn) * HWn;
    __shared__ float kt[32][129];
    __shared__ float qt[128];
    __shared__ float red[256];
    float acc = 0.f;
    for (int t0 = 0; t0 < HWn; t0 += 128) {
        __syncthreads();
        if (tid < 128) qt[tid] = b2f(qrow[t0 + tid]);
        for (int i = tid; i < 32 * 128; i += 256) {
            int dd = i >> 7, nn = i & 127;
            kt[dd][nn] = b2f(kbase[(size_t)dd * HWn + t0 + nn]);
        }
        __syncthreads();
        #pragma unroll
        for (int i = 0; i < 16; i++) {
            int nn = s * 16 + i;
            acc += qt[nn] * kt[d][nn];
        }
    }
    red[tid] = acc; __syncthreads();
    if (tid < 128) red[tid] += red[tid + 128];
    __syncthreads();
    if (tid < 64) red[tid] += red[tid + 64];
    __syncthreads();
    if (tid < 32) {
        float v = red[tid] + red[tid + 32];
        v *= qs[b * Cn + h * CHn + c] * ks[b * Cn + h * CHn + tid] * temp[h];
        float m = v;
        for (int off = 16; off > 0; off >>= 1) m = fmaxf(m, __shfl_xor(m, off));
        float e = __expf(v - m);
        float ssum = e;
        for (int off = 16; off > 0; off >>= 1) ssum += __shfl_xor(ssum, off);
        attn[((size_t)bh * 32 + c) * 32 + tid] = e / ssum;
    }
}

// ---------------- out = attn @ v ----------------
__global__ void av_kernel(const float* __restrict__ attn,
                          const bf16* __restrict__ kvdw,
                          bf16* __restrict__ out) {
    int bh = blockIdx.y;
    int b = bh >> 3, h = bh & 7;
    int tid = threadIdx.x;
    int n = blockIdx.x * 256 + tid;
    __shared__ float At[32][32];
    for (int i = tid; i < 1024; i += 256) {
        int cc = i >> 5, dd = i & 31;
        At[dd][cc] = attn[((size_t)bh * 32 + cc) * 32 + dd];
    }
    __syncthreads();
    const bf16* vbase = kvdw + ((size_t)b * C2n + Cn + h * CHn) * HWn;
    float acc[32];
    #pragma unroll
    for (int c = 0; c < 32; c++) acc[c] = 0.f;
    for (int d = 0; d < 32; d++) {
        float vv = b2f(vbase[(size_t)d * HWn + n]);
        #pragma unroll
        for (int c = 0; c < 32; c++) acc[c] += At[d][c] * vv;
    }
    bf16* obase = out + ((size_t)b * Cn + h * CHn) * HWn + n;
    #pragma unroll
    for (int c = 0; c < 32; c++) obase[(size_t)c * HWn] = f2b(acc[c]);
}

// ---------------- proj 1x1 + residual ----------------
__global__ void proj_kernel(const bf16* __restrict__ ao,
                            const float* __restrict__ Wp,
                            const float* __restrict__ yn32,
                            float* __restrict__ out) {
    __shared__ float wT[Cn][OCB];
    int tid = threadIdx.x;
    int oc0 = blockIdx.y * OCB;
    int b   = blockIdx.z;
    for (int i = tid; i < Cn * OCB; i += 256) {
        int j = i & (OCB - 1);
        int c = i >> 3;
        wT[c][j] = Wp[(size_t)(oc0 + j) * Cn + c];
    }
    __syncthreads();
    int hw = blockIdx.x * 256 + tid;
    const bf16* ab = ao + (size_t)b * Cn * HWn + hw;
    float acc[OCB] = {0.f, 0.f, 0.f, 0.f, 0.f, 0.f, 0.f, 0.f};
    for (int c = 0; c < Cn; c++) {
        float v = b2f(ab[(size_t)c * HWn]);
        #pragma unroll
        for (int j = 0; j < OCB; j++) acc[j] += wT[c][j] * v;
    }
    #pragma unroll
    for (int j = 0; j < OCB; j++) {
        size_t idx = ((size_t)b * Cn + oc0 + j) * HWn + hw;
        out[idx] = yn32[idx] + acc[j];
    }
}

extern "C" void kernel_launch(void* const* d_in, const int* in_sizes, int n_in,
                              void* d_out, int out_size, void* d_ws, size_t ws_size,
                              hipStream_t stream) {
    const float* x     = (const float*)d_in[0];
    const float* y     = (const float*)d_in[1];
    const float* lnkw  = (const float*)d_in[2];
    const float* lnkb  = (const float*)d_in[3];
    const float* lnqw  = (const float*)d_in[4];
    const float* lnqb  = (const float*)d_in[5];
    const float* Wkv   = (const float*)d_in[6];
    const float* Wdw   = (const float*)d_in[7];
    const float* Wq    = (const float*)d_in[8];
    const float* Wproj = (const float*)d_in[9];
    const float* temp  = (const float*)d_in[10];
    float* out = (float*)d_out;

    char* ws = (char*)d_ws;
    const size_t TEN = (size_t)Bn * Cn * HWn;          // 16,777,216 elems
    bf16*  bufA  = (bf16*)(ws);                        // 32 MB: xn -> q -> ao
    bf16*  bufB  = (bf16*)(ws + TEN * 2);              // 32 MB: yn (bf16 cm)
    bf16*  kvdw  = (bf16*)(ws + TEN * 4);              // 64 MB
    float* yn32  = (float*)(ws + TEN * 8);             // 64 MB: yn f32 (residual)
    bf16*  yn_pm = (bf16*)(ws + TEN * 12);             // 32 MB: yn pixel-major
    bf16*  wq_pk = (bf16*)(ws + TEN * 14);             // 1.2 MB packed Wq
    char*  wp    = ws + TEN * 14 + 1179648;
    float* qs    = (float*)(wp);          wp += 4096;
    float* ksr   = (float*)(wp);          wp += 4096;
    float* attnP = (float*)(wp);          wp += 131072;   // ~236 MB total

    // 0. weight repack for MFMA qconv
    wq_repack_kernel<<<dim3(256), 256, 0, stream>>>(Wq, wq_pk);
    // 1-2. LayerNorms
    ln_kernel<<<dim3(Bn * HWn / 256), 256, 0, stream>>>(x, lnkw, lnkb, bufA, nullptr); // xn
    ln_kernel<<<dim3(Bn * HWn / 256), 256, 0, stream>>>(y, lnqw, lnqb, bufB, yn32);    // yn
    // 3. yn -> pixel-major for MFMA B-tiles
    transpose_kernel<<<dim3(HWn / 64, Cn / 64, Bn), 256, 0, stream>>>(bufB, yn_pm);
    // 4. fused kv: dw3x3(conv1x1(xn)) -> kvdw
    fused_kv_kernel<<<dim3(Hn / STRIP, C2n / OCB, Bn), 256, 0, stream>>>(bufA, Wkv, Wdw, kvdw);
    // 5. q = 3x3 conv via MFMA -> bufA (xn dead after fused_kv)
    qconv_mfma_kernel<<<dim3(Hn, 2, Bn), 256, 0, stream>>>(yn_pm, wq_pk, bufA);
    // 6. L2-norm scales for q and k
    norm_kernel<<<dim3(Bn * Cn, 2), 256, 0, stream>>>(bufA, kvdw, qs, ksr);
    // 7. attention logits + softmax
    attn_kernel<<<dim3(CHn, Bn * HEADSn), 256, 0, stream>>>(bufA, kvdw, qs, ksr, temp, attnP);
    // 8. attn @ v -> bufA (q dead after attn)
    av_kernel<<<dim3(HWn / 256, Bn * HEADSn), 256, 0, stream>>>(attnP, kvdw, bufA);
    // 9. proj 1x1 + residual -> final f32 output
    proj_kernel<<<dim3(HWn / 256, Cn / OCB, Bn), 256, 0, stream>>>(bufA, Wproj, yn32, out);
}

// Round 7
// 777.879 us; speedup vs baseline: 5.0275x; 2.7586x over previous
//
#include <hip/hip_runtime.h>
#include <hip/hip_bf16.h>

typedef __hip_bfloat16 bf16;
typedef __attribute__((ext_vector_type(8))) short bf16x8;
typedef __attribute__((ext_vector_type(4))) float f32x4;

#define Bn 4
#define Cn 256
#define C2n 512
#define Hn 128
#define Wn 128
#define HWn 16384
#define HEADSn 8
#define CHn 32
#define LDP 40   // 32 + 8 pad shorts; 80 B rows (16B-aligned)

static __device__ __forceinline__ float b2f(bf16 v) { return __bfloat162float(v); }
static __device__ __forceinline__ bf16 f2b(float v) { return __float2bfloat16(v); }
// bit-exact lane conversions (NEVER assign bf16 <-> short numerically)
static __device__ __forceinline__ short f2bs(float v) {
    bf16 t = f2b(v);
    return __builtin_bit_cast(short, t);
}
static __device__ __forceinline__ float s2f(short s) {
    bf16 t = __builtin_bit_cast(bf16, s);
    return b2f(t);
}

// ---------------- f32 -> bf16 cast ----------------
__global__ void cast_kernel(const float* __restrict__ src, bf16* __restrict__ dst, int n) {
    for (int i = blockIdx.x * 256 + threadIdx.x; i < n; i += gridDim.x * 256)
        dst[i] = f2b(src[i]);
}

// ---------------- repack Wq: f32 [oc][c][3][3] -> bf16 [tap][oc][c] ----------------
__global__ void wq_repack_kernel(const float* __restrict__ Wq, bf16* __restrict__ wp) {
    int i = blockIdx.x * 256 + threadIdx.x;     // over oc*c = 65536
    if (i < Cn * Cn) {
        #pragma unroll
        for (int t = 0; t < 9; t++)
            wp[(size_t)t * Cn * Cn + i] = f2b(Wq[(size_t)i * 9 + t]);
    }
}

// ---------------- LayerNorm over channel dim (per pixel) ----------------
__global__ void ln_kernel(const float* __restrict__ x,
                          const float* __restrict__ gw,
                          const float* __restrict__ gb,
                          bf16* __restrict__ o16) {
    __shared__ float sw[Cn], sb[Cn];
    int tid = threadIdx.x;
    if (tid < Cn) { sw[tid] = gw[tid]; sb[tid] = gb[tid]; }
    __syncthreads();
    int pix = blockIdx.x * 256 + tid;
    int b = pix >> 14;
    int hw = pix & (HWn - 1);
    const float* xb = x + (size_t)b * Cn * HWn + hw;
    float s = 0.f, ss = 0.f;
    for (int c = 0; c < Cn; c++) {
        float v = xb[(size_t)c * HWn];
        s += v; ss += v * v;
    }
    float mu  = s * (1.f / Cn);
    float var = ss * (1.f / Cn) - mu * mu;
    float inv = rsqrtf(var + 1e-5f);
    bf16* ob = o16 + (size_t)b * Cn * HWn + hw;
    for (int c = 0; c < Cn; c++) {
        float v = (xb[(size_t)c * HWn] - mu) * inv * sw[c] + sb[c];
        ob[(size_t)c * HWn] = f2b(v);
    }
}

// ---------------- transpose: [b][c][hw] bf16 -> [b][hw][c] bf16 ----------------
__global__ void transpose_kernel(const bf16* __restrict__ src, bf16* __restrict__ dst) {
    __shared__ unsigned int t[64][65];
    int tid = threadIdx.x;
    int pxt = blockIdx.x;
    int ct  = blockIdx.y;
    int b   = blockIdx.z;
    const bf16* sb = src + ((size_t)b * Cn + ct * 64) * HWn + pxt * 64;
    for (int i = tid; i < 512; i += 256) {
        int r = i >> 3, sg = (i & 7) * 8;
        bf16x8 v = *(const bf16x8*)&sb[(size_t)r * HWn + sg];
        #pragma unroll
        for (int j = 0; j < 8; j++) t[r][sg + j] = (unsigned int)(unsigned short)v[j];
    }
    __syncthreads();
    bf16* db = dst + ((size_t)b * HWn + pxt * 64) * Cn + ct * 64;
    for (int i = tid; i < 512; i += 256) {
        int r = i >> 3, sg = (i & 7) * 8;
        bf16x8 v;
        #pragma unroll
        for (int j = 0; j < 8; j++) v[j] = (short)(unsigned short)t[sg + j][r];
        *(bf16x8*)&db[(size_t)r * Cn + sg] = v;
    }
}

// ---------------- kv 1x1 conv as GEMM via MFMA ----------------
__global__ __launch_bounds__(256) void kv1x1_mfma_kernel(
        const bf16* __restrict__ xn_pm,    // [b][px][c]
        const bf16* __restrict__ wkv_pk,   // [oc][c] bf16 (512x256)
        bf16* __restrict__ kv) {           // [b][oc][px]
    __shared__ short Als[128 * LDP];
    __shared__ short Bls[128 * LDP];
    int tid  = threadIdx.x;
    int px0  = blockIdx.x * 128;
    int oc0  = blockIdx.y * 128;
    int b    = blockIdx.z;
    int wave = tid >> 6, lane = tid & 63;
    int lm = lane & 15, kq = lane >> 4;
    int k0 = kq * 8;

    f32x4 acc[2][8];
    #pragma unroll
    for (int mt = 0; mt < 2; mt++)
        #pragma unroll
        for (int nt = 0; nt < 8; nt++) acc[mt][nt] = (f32x4){0.f, 0.f, 0.f, 0.f};

    const short* xb = (const short*)(xn_pm + ((size_t)b * HWn + px0) * Cn);
    const short* wb = (const short*)wkv_pk + (size_t)oc0 * Cn;

    for (int kc = 0; kc < Cn; kc += 32) {
        __syncthreads();
        for (int i = tid; i < 512; i += 256) {
            int r = i >> 2, sg = (i & 3) * 8;
            *(bf16x8*)&Als[r * LDP + sg] = *(const bf16x8*)&wb[(size_t)r * Cn + kc + sg];
            *(bf16x8*)&Bls[r * LDP + sg] = *(const bf16x8*)&xb[(size_t)r * Cn + kc + sg];
        }
        __syncthreads();
        bf16x8 afr[2], bfr[8];
        #pragma unroll
        for (int mt = 0; mt < 2; mt++)
            afr[mt] = *(const bf16x8*)&Als[(wave * 32 + mt * 16 + lm) * LDP + k0];
        #pragma unroll
        for (int nt = 0; nt < 8; nt++)
            bfr[nt] = *(const bf16x8*)&Bls[(nt * 16 + lm) * LDP + k0];
        #pragma unroll
        for (int mt = 0; mt < 2; mt++)
            #pragma unroll
            for (int nt = 0; nt < 8; nt++)
                acc[mt][nt] = __builtin_amdgcn_mfma_f32_16x16x32_bf16(
                    afr[mt], bfr[nt], acc[mt][nt], 0, 0, 0);
    }
    bf16* kb = kv + ((size_t)b * C2n + oc0) * HWn + px0;
    #pragma unroll
    for (int mt = 0; mt < 2; mt++) {
        int ocl = wave * 32 + mt * 16 + kq * 4;
        #pragma unroll
        for (int nt = 0; nt < 8; nt++) {
            int px = nt * 16 + lm;
            #pragma unroll
            for (int r = 0; r < 4; r++)
                kb[(size_t)(ocl + r) * HWn + px] = f2b(acc[mt][nt][r]);
        }
    }
}

// ---------------- depthwise 3x3 SAME, vectorized via LDS strip ----------------
__global__ void dw_kernel(const bf16* __restrict__ kv,
                          const float* __restrict__ Wdw,
                          bf16* __restrict__ kvdw) {
    __shared__ float st[18][132];
    int tid = threadIdx.x;
    int r0  = blockIdx.x * 16;
    int ch  = blockIdx.y;
    int b   = blockIdx.z;
    float w[9];
    #pragma unroll
    for (int t = 0; t < 9; t++) w[t] = Wdw[ch * 9 + t];
    const bf16* base = kv + ((size_t)b * C2n + ch) * HWn;
    if (tid < 18) { st[tid][0] = 0.f; st[tid][129] = 0.f; }
    for (int i = tid; i < 288; i += 256) {
        int row = i >> 4, sg = (i & 15) << 3;
        int gr = r0 - 1 + row;
        bf16x8 v = {0, 0, 0, 0, 0, 0, 0, 0};
        if (gr >= 0 && gr < Hn) v = *(const bf16x8*)&base[(size_t)gr * Wn + sg];
        #pragma unroll
        for (int j = 0; j < 8; j++) st[row][1 + sg + j] = s2f(v[j]);
    }
    __syncthreads();
    int orow = tid >> 4, sg = (tid & 15) << 3;
    float o[8];
    #pragma unroll
    for (int j = 0; j < 8; j++) o[j] = 0.f;
    #pragma unroll
    for (int dy = 0; dy < 3; dy++)
        #pragma unroll
        for (int dx = 0; dx < 3; dx++) {
            float ww = w[dy * 3 + dx];
            #pragma unroll
            for (int j = 0; j < 8; j++) o[j] += ww * st[orow + dy][sg + j + dx];
        }
    bf16x8 ov;
    #pragma unroll
    for (int j = 0; j < 8; j++) ov[j] = f2bs(o[j]);
    *(bf16x8*)&kvdw[((size_t)b * C2n + ch) * HWn + (size_t)(r0 + orow) * Wn + sg] = ov;
}

// ---------------- q conv 3x3 as implicit GEMM via MFMA ----------------
__global__ __launch_bounds__(256) void qconv_mfma_kernel(
        const bf16* __restrict__ yn_pm,    // [b][px][c]
        const bf16* __restrict__ wq_pk,    // [tap][oc][c]
        bf16* __restrict__ q) {            // [b][oc][px]
    __shared__ short Als[128 * LDP];
    __shared__ short Bls[128 * LDP];
    int tid  = threadIdx.x;
    int y    = blockIdx.x;
    int oc0  = blockIdx.y * 128;
    int b    = blockIdx.z;
    int wave = tid >> 6, lane = tid & 63;
    int lm = lane & 15, kq = lane >> 4;
    int k0 = kq * 8;

    f32x4 acc[2][8];
    #pragma unroll
    for (int mt = 0; mt < 2; mt++)
        #pragma unroll
        for (int nt = 0; nt < 8; nt++) acc[mt][nt] = (f32x4){0.f, 0.f, 0.f, 0.f};

    const short* ypb = (const short*)(yn_pm + (size_t)b * HWn * Cn);

    for (int tap = 0; tap < 9; tap++) {
        int dy = tap / 3 - 1, dx = tap % 3 - 1;
        int yy = y + dy;
        if (yy < 0 || yy >= Hn) continue;
        const short* wtap  = (const short*)(wq_pk + (size_t)tap * Cn * Cn);
        const short* ybase = ypb + (size_t)yy * Wn * Cn;
        for (int kc = 0; kc < Cn; kc += 32) {
            __syncthreads();
            for (int i = tid; i < 512; i += 256) {
                int r = i >> 2, sg = (i & 3) * 8;
                *(bf16x8*)&Als[r * LDP + sg] =
                    *(const bf16x8*)&wtap[(size_t)(oc0 + r) * Cn + kc + sg];
                int xs = r + dx;
                bf16x8 v = {0, 0, 0, 0, 0, 0, 0, 0};
                if (xs >= 0 && xs < Wn)
                    v = *(const bf16x8*)&ybase[(size_t)xs * Cn + kc + sg];
                *(bf16x8*)&Bls[r * LDP + sg] = v;
            }
            __syncthreads();
            bf16x8 afr[2], bfr[8];
            #pragma unroll
            for (int mt = 0; mt < 2; mt++)
                afr[mt] = *(const bf16x8*)&Als[(wave * 32 + mt * 16 + lm) * LDP + k0];
            #pragma unroll
            for (int nt = 0; nt < 8; nt++)
                bfr[nt] = *(const bf16x8*)&Bls[(nt * 16 + lm) * LDP + k0];
            #pragma unroll
            for (int mt = 0; mt < 2; mt++)
                #pragma unroll
                for (int nt = 0; nt < 8; nt++)
                    acc[mt][nt] = __builtin_amdgcn_mfma_f32_16x16x32_bf16(
                        afr[mt], bfr[nt], acc[mt][nt], 0, 0, 0);
        }
    }
    bf16* qb = q + ((size_t)b * Cn + oc0) * HWn + (size_t)y * Wn;
    #pragma unroll
    for (int mt = 0; mt < 2; mt++) {
        int ocl = wave * 32 + mt * 16 + kq * 4;
        #pragma unroll
        for (int nt = 0; nt < 8; nt++) {
            int px = nt * 16 + lm;
            #pragma unroll
            for (int r = 0; r < 4; r++)
                qb[(size_t)(ocl + r) * HWn + px] = f2b(acc[mt][nt][r]);
        }
    }
}

// ---------------- per-row rsqrt(sumsq) scales for q and k ----------------
__global__ void norm_kernel(const bf16* __restrict__ q,
                            const bf16* __restrict__ kvdw,
                            float* __restrict__ qs,
                            float* __restrict__ ks) {
    int row = blockIdx.x;
    int b = row >> 8, c = row & 255;
    int tid = threadIdx.x;
    const bf16* src = (blockIdx.y == 0)
        ? q    + ((size_t)b * Cn  + c) * HWn
        : kvdw + ((size_t)b * C2n + c) * HWn;
    float ssum = 0.f;
    for (int i = tid; i < HWn; i += 256) {
        float v = b2f(src[i]);
        ssum += v * v;
    }
    __shared__ float red[256];
    red[tid] = ssum; __syncthreads();
    if (tid < 128) red[tid] += red[tid + 128];
    __syncthreads();
    if (tid < 64) red[tid] += red[tid + 64];
    __syncthreads();
    if (tid < 32) {
        float v = red[tid] + red[tid + 32];
        for (int off = 16; off > 0; off >>= 1) v += __shfl_xor(v, off);
        if (tid == 0) {
            float* dst = (blockIdx.y == 0) ? qs : ks;
            dst[row] = 1.f / fmaxf(sqrtf(v), 1e-12f);
        }
    }
}

// ---------------- attn logits + softmax ----------------
__global__ void attn_kernel(const bf16* __restrict__ q,
                            const bf16* __restrict__ kvdw,
                            const float* __restrict__ qs,
                            const float* __restrict__ ks,
                            const float* __restrict__ temp,
                            float* __restrict__ attn) {
    int c  = blockIdx.x;
    int bh = blockIdx.y;
    int b = bh >> 3, h = bh & 7;
    int tid = threadIdx.x;
    int d = tid & 31, s = tid >> 5;
    const bf16* qrow  = q    + ((size_t)b * Cn + h * CHn + c) * HWn;
    const bf16* kbase = kvdw + ((size_t)b * C2n + h * CHn) * HWn;
    __shared__ float kt[32][129];
    __shared__ float qt[128];
    __shared__ float red[256];
    float acc = 0.f;
    for (int t0 = 0; t0 < HWn; t0 += 128) {
        __syncthreads();
        if (tid < 128) qt[tid] = b2f(qrow[t0 + tid]);
        for (int i = tid; i < 32 * 128; i += 256) {
            int dd = i >> 7, nn = i & 127;
            kt[dd][nn] = b2f(kbase[(size_t)dd * HWn + t0 + nn]);
        }
        __syncthreads();
        #pragma unroll
        for (int i = 0; i < 16; i++) {
            int nn = s * 16 + i;
            acc += qt[nn] * kt[d][nn];
        }
    }
    red[tid] = acc; __syncthreads();
    if (tid < 128) red[tid] += red[tid + 128];
    __syncthreads();
    if (tid < 64) red[tid] += red[tid + 64];
    __syncthreads();
    if (tid < 32) {
        float v = red[tid] + red[tid + 32];
        v *= qs[b * Cn + h * CHn + c] * ks[b * Cn + h * CHn + tid] * temp[h];
        float m = v;
        for (int off = 16; off > 0; off >>= 1) m = fmaxf(m, __shfl_xor(m, off));
        float e = __expf(v - m);
        float ssum = e;
        for (int off = 16; off > 0; off >>= 1) ssum += __shfl_xor(ssum, off);
        attn[((size_t)bh * 32 + c) * 32 + tid] = e / ssum;
    }
}

// ---------------- out = attn @ v  (writes PIXEL-MAJOR) ----------------
__global__ void av_kernel(const float* __restrict__ attn,
                          const bf16* __restrict__ kvdw,
                          bf16* __restrict__ ao_pm) {
    int bh = blockIdx.y;
    int b = bh >> 3, h = bh & 7;
    int tid = threadIdx.x;
    int n = blockIdx.x * 256 + tid;
    __shared__ float At[32][32];
    for (int i = tid; i < 1024; i += 256) {
        int cc = i >> 5, dd = i & 31;
        At[dd][cc] = attn[((size_t)bh * 32 + cc) * 32 + dd];
    }
    __syncthreads();
    const bf16* vbase = kvdw + ((size_t)b * C2n + Cn + h * CHn) * HWn;
    float acc[32];
    #pragma unroll
    for (int c = 0; c < 32; c++) acc[c] = 0.f;
    for (int d = 0; d < 32; d++) {
        float vv = b2f(vbase[(size_t)d * HWn + n]);
        #pragma unroll
        for (int c = 0; c < 32; c++) acc[c] += At[d][c] * vv;
    }
    bf16* obase = ao_pm + ((size_t)b * HWn + n) * Cn + h * CHn;
    #pragma unroll
    for (int g = 0; g < 4; g++) {
        bf16x8 v;
        #pragma unroll
        for (int j = 0; j < 8; j++) v[j] = f2bs(acc[g * 8 + j]);
        *(bf16x8*)&obase[g * 8] = v;
    }
}

// ---------------- proj 1x1 via MFMA + residual (writes final f32) ----------------
__global__ __launch_bounds__(256) void proj_mfma_kernel(
        const bf16* __restrict__ ao_pm,    // [b][px][c]
        const bf16* __restrict__ wpr_pk,   // [oc][c] bf16 (256x256)
        const bf16* __restrict__ yn_pm,    // [b][px][c] (residual)
        float* __restrict__ out) {         // [b][oc][px] f32
    __shared__ short Als[128 * LDP];
    __shared__ short Bls[128 * LDP];
    int tid  = threadIdx.x;
    int px0  = blockIdx.x * 128;
    int oc0  = blockIdx.y * 128;
    int b    = blockIdx.z;
    int wave = tid >> 6, lane = tid & 63;
    int lm = lane & 15, kq = lane >> 4;
    int k0 = kq * 8;

    f32x4 acc[2][8];
    #pragma unroll
    for (int mt = 0; mt < 2; mt++)
        #pragma unroll
        for (int nt = 0; nt < 8; nt++) acc[mt][nt] = (f32x4){0.f, 0.f, 0.f, 0.f};

    const short* ab = (const short*)(ao_pm + ((size_t)b * HWn + px0) * Cn);
    const short* wb = (const short*)wpr_pk + (size_t)oc0 * Cn;

    for (int kc = 0; kc < Cn; kc += 32) {
        __syncthreads();
        for (int i = tid; i < 512; i += 256) {
            int r = i >> 2, sg = (i & 3) * 8;
            *(bf16x8*)&Als[r * LDP + sg] = *(const bf16x8*)&wb[(size_t)r * Cn + kc + sg];
            *(bf16x8*)&Bls[r * LDP + sg] = *(const bf16x8*)&ab[(size_t)r * Cn + kc + sg];
        }
        __syncthreads();
        bf16x8 afr[2], bfr[8];
        #pragma unroll
        for (int mt = 0; mt < 2; mt++)
            afr[mt] = *(const bf16x8*)&Als[(wave * 32 + mt * 16 + lm) * LDP + k0];
        #pragma unroll
        for (int nt = 0; nt < 8; nt++)
            bfr[nt] = *(const bf16x8*)&Bls[(nt * 16 + lm) * LDP + k0];
        #pragma unroll
        for (int mt = 0; mt < 2; mt++)
            #pragma unroll
            for (int nt = 0; nt < 8; nt++)
                acc[mt][nt] = __builtin_amdgcn_mfma_f32_16x16x32_bf16(
                    afr[mt], bfr[nt], acc[mt][nt], 0, 0, 0);
    }
    const bf16* ynb = yn_pm + ((size_t)b * HWn + px0) * Cn;
    float* ob = out + ((size_t)b * Cn + oc0) * HWn + px0;
    #pragma unroll
    for (int mt = 0; mt < 2; mt++) {
        int ocl = wave * 32 + mt * 16 + kq * 4;
        #pragma unroll
        for (int nt = 0; nt < 8; nt++) {
            int px = nt * 16 + lm;
            #pragma unroll
            for (int r = 0; r < 4; r++)
                ob[(size_t)(ocl + r) * HWn + px] =
                    acc[mt][nt][r] + b2f(ynb[(size_t)px * Cn + oc0 + ocl + r]);
        }
    }
}

extern "C" void kernel_launch(void* const* d_in, const int* in_sizes, int n_in,
                              void* d_out, int out_size, void* d_ws, size_t ws_size,
                              hipStream_t stream) {
    const float* x     = (const float*)d_in[0];
    const float* y     = (const float*)d_in[1];
    const float* lnkw  = (const float*)d_in[2];
    const float* lnkb  = (const float*)d_in[3];
    const float* lnqw  = (const float*)d_in[4];
    const float* lnqb  = (const float*)d_in[5];
    const float* Wkv   = (const float*)d_in[6];
    const float* Wdw   = (const float*)d_in[7];
    const float* Wq    = (const float*)d_in[8];
    const float* Wproj = (const float*)d_in[9];
    const float* temp  = (const float*)d_in[10];
    float* out = (float*)d_out;

    char* ws = (char*)d_ws;
    const size_t TEN = (size_t)Bn * Cn * HWn;          // 16,777,216 elems
    // R0 [0, 64 MiB): xn_cm | yn_cm  ->  kv  ->  q_cm
    bf16* xn_cm = (bf16*)ws;
    bf16* yn_cm = (bf16*)(ws + TEN * 2);
    bf16* kv    = (bf16*)ws;
    bf16* q_cm  = (bf16*)ws;
    // R1 [64, 128 MiB): kvdw
    bf16* kvdw  = (bf16*)(ws + TEN * 4);
    // R2 [128, 160 MiB): xn_pm -> ao_pm
    bf16* xn_pm = (bf16*)(ws + TEN * 8);
    bf16* ao_pm = xn_pm;
    // R3 [160, 192 MiB): yn_pm (lives until proj residual)
    bf16* yn_pm = (bf16*)(ws + TEN * 10);
    // small buffers
    char* wp = ws + TEN * 12;
    bf16* wq_pk  = (bf16*)wp;  wp += 589824 * 2;
    bf16* wkv_pk = (bf16*)wp;  wp += 131072 * 2;
    bf16* wpr_pk = (bf16*)wp;  wp += 65536 * 2;
    float* qs    = (float*)wp; wp += 4096;
    float* ksr   = (float*)wp; wp += 4096;
    float* attnP = (float*)wp; wp += 131072;

    // 0. weight preprocessing
    wq_repack_kernel<<<dim3(256), 256, 0, stream>>>(Wq, wq_pk);
    cast_kernel<<<dim3(128), 256, 0, stream>>>(Wkv, wkv_pk, C2n * Cn);
    cast_kernel<<<dim3(64), 256, 0, stream>>>(Wproj, wpr_pk, Cn * Cn);
    // 1-2. LayerNorms (channel-major bf16)
    ln_kernel<<<dim3(Bn * HWn / 256), 256, 0, stream>>>(x, lnkw, lnkb, xn_cm);
    ln_kernel<<<dim3(Bn * HWn / 256), 256, 0, stream>>>(y, lnqw, lnqb, yn_cm);
    // 3-4. transposes to pixel-major
    transpose_kernel<<<dim3(HWn / 64, Cn / 64, Bn), 256, 0, stream>>>(xn_cm, xn_pm);
    transpose_kernel<<<dim3(HWn / 64, Cn / 64, Bn), 256, 0, stream>>>(yn_cm, yn_pm);
    // 5. kv = 1x1 conv via MFMA (overwrites xn_cm/yn_cm region — both dead)
    kv1x1_mfma_kernel<<<dim3(HWn / 128, C2n / 128, Bn), 256, 0, stream>>>(xn_pm, wkv_pk, kv);
    // 6. depthwise 3x3 -> kvdw
    dw_kernel<<<dim3(Hn / 16, C2n, Bn), 256, 0, stream>>>(kv, Wdw, kvdw);
    // 7. q = 3x3 conv via MFMA -> q_cm (kv dead after dw)
    qconv_mfma_kernel<<<dim3(Hn, Cn / 128, Bn), 256, 0, stream>>>(yn_pm, wq_pk, q_cm);
    // 8. L2-norm scales
    norm_kernel<<<dim3(Bn * Cn, 2), 256, 0, stream>>>(q_cm, kvdw, qs, ksr);
    // 9. attention logits + softmax
    attn_kernel<<<dim3(CHn, Bn * HEADSn), 256, 0, stream>>>(q_cm, kvdw, qs, ksr, temp, attnP);
    // 10. attn @ v -> ao_pm (xn_pm dead after kv1x1)
    av_kernel<<<dim3(HWn / 256, Bn * HEADSn), 256, 0, stream>>>(attnP, kvdw, ao_pm);
    // 11. proj 1x1 via MFMA + residual -> final f32 output
    proj_mfma_kernel<<<dim3(HWn / 128, Cn / 128, Bn), 256, 0, stream>>>(ao_pm, wpr_pk, yn_pm, out);
}

// Round 8
// 590.066 us; speedup vs baseline: 6.6277x; 1.3183x over previous
//
#include <hip/hip_runtime.h>
#include <hip/hip_bf16.h>

typedef __hip_bfloat16 bf16;
typedef __attribute__((ext_vector_type(8))) short bf16x8;
typedef __attribute__((ext_vector_type(4))) float f32x4;

#define Bn 4
#define Cn 256
#define C2n 512
#define Hn 128
#define Wn 128
#define HWn 16384
#define HEADSn 8
#define CHn 32
#define LDP 40   // 32 + 8 pad shorts; 80 B rows (16B-aligned)

static __device__ __forceinline__ float b2f(bf16 v) { return __bfloat162float(v); }
static __device__ __forceinline__ bf16 f2b(float v) { return __float2bfloat16(v); }
// bit-exact lane conversions (NEVER assign bf16 <-> short numerically)
static __device__ __forceinline__ short f2bs(float v) {
    bf16 t = f2b(v);
    return __builtin_bit_cast(short, t);
}
static __device__ __forceinline__ float s2f(short s) {
    bf16 t = __builtin_bit_cast(bf16, s);
    return b2f(t);
}

// ---------------- f32 -> bf16 cast ----------------
__global__ void cast_kernel(const float* __restrict__ src, bf16* __restrict__ dst, int n) {
    for (int i = blockIdx.x * 256 + threadIdx.x; i < n; i += gridDim.x * 256)
        dst[i] = f2b(src[i]);
}

// ---------------- repack Wq: f32 [oc][c][3][3] -> bf16 [tap][oc][c] ----------------
__global__ void wq_repack_kernel(const float* __restrict__ Wq, bf16* __restrict__ wp) {
    int i = blockIdx.x * 256 + threadIdx.x;     // over oc*c = 65536
    if (i < Cn * Cn) {
        #pragma unroll
        for (int t = 0; t < 9; t++)
            wp[(size_t)t * Cn * Cn + i] = f2b(Wq[(size_t)i * 9 + t]);
    }
}

// ---------------- LayerNorm over channel dim (per pixel) ----------------
__global__ void ln_kernel(const float* __restrict__ x,
                          const float* __restrict__ gw,
                          const float* __restrict__ gb,
                          bf16* __restrict__ o16) {
    __shared__ float sw[Cn], sb[Cn];
    int tid = threadIdx.x;
    if (tid < Cn) { sw[tid] = gw[tid]; sb[tid] = gb[tid]; }
    __syncthreads();
    int pix = blockIdx.x * 256 + tid;
    int b = pix >> 14;
    int hw = pix & (HWn - 1);
    const float* xb = x + (size_t)b * Cn * HWn + hw;
    float s = 0.f, ss = 0.f;
    for (int c = 0; c < Cn; c++) {
        float v = xb[(size_t)c * HWn];
        s += v; ss += v * v;
    }
    float mu  = s * (1.f / Cn);
    float var = ss * (1.f / Cn) - mu * mu;
    float inv = rsqrtf(var + 1e-5f);
    bf16* ob = o16 + (size_t)b * Cn * HWn + hw;
    for (int c = 0; c < Cn; c++) {
        float v = (xb[(size_t)c * HWn] - mu) * inv * sw[c] + sb[c];
        ob[(size_t)c * HWn] = f2b(v);
    }
}

// ---------------- transpose: [b][c][hw] bf16 -> [b][hw][c] bf16 ----------------
__global__ void transpose_kernel(const bf16* __restrict__ src, bf16* __restrict__ dst) {
    __shared__ unsigned int t[64][65];
    int tid = threadIdx.x;
    int pxt = blockIdx.x;
    int ct  = blockIdx.y;
    int b   = blockIdx.z;
    const bf16* sb = src + ((size_t)b * Cn + ct * 64) * HWn + pxt * 64;
    for (int i = tid; i < 512; i += 256) {
        int r = i >> 3, sg = (i & 7) * 8;
        bf16x8 v = *(const bf16x8*)&sb[(size_t)r * HWn + sg];
        #pragma unroll
        for (int j = 0; j < 8; j++) t[r][sg + j] = (unsigned int)(unsigned short)v[j];
    }
    __syncthreads();
    bf16* db = dst + ((size_t)b * HWn + pxt * 64) * Cn + ct * 64;
    for (int i = tid; i < 512; i += 256) {
        int r = i >> 3, sg = (i & 7) * 8;
        bf16x8 v;
        #pragma unroll
        for (int j = 0; j < 8; j++) v[j] = (short)(unsigned short)t[sg + j][r];
        *(bf16x8*)&db[(size_t)r * Cn + sg] = v;
    }
}

// ---------------- kv 1x1 conv as GEMM via MFMA ----------------
__global__ __launch_bounds__(256) void kv1x1_mfma_kernel(
        const bf16* __restrict__ xn_pm,    // [b][px][c]
        const bf16* __restrict__ wkv_pk,   // [oc][c] bf16 (512x256)
        bf16* __restrict__ kv) {           // [b][oc][px]
    __shared__ short Als[128 * LDP];
    __shared__ short Bls[128 * LDP];
    int tid  = threadIdx.x;
    int px0  = blockIdx.x * 128;
    int oc0  = blockIdx.y * 128;
    int b    = blockIdx.z;
    int wave = tid >> 6, lane = tid & 63;
    int lm = lane & 15, kq = lane >> 4;
    int k0 = kq * 8;

    f32x4 acc[2][8];
    #pragma unroll
    for (int mt = 0; mt < 2; mt++)
        #pragma unroll
        for (int nt = 0; nt < 8; nt++) acc[mt][nt] = (f32x4){0.f, 0.f, 0.f, 0.f};

    const short* xb = (const short*)(xn_pm + ((size_t)b * HWn + px0) * Cn);
    const short* wb = (const short*)wkv_pk + (size_t)oc0 * Cn;

    for (int kc = 0; kc < Cn; kc += 32) {
        __syncthreads();
        for (int i = tid; i < 512; i += 256) {
            int r = i >> 2, sg = (i & 3) * 8;
            *(bf16x8*)&Als[r * LDP + sg] = *(const bf16x8*)&wb[(size_t)r * Cn + kc + sg];
            *(bf16x8*)&Bls[r * LDP + sg] = *(const bf16x8*)&xb[(size_t)r * Cn + kc + sg];
        }
        __syncthreads();
        bf16x8 afr[2], bfr[8];
        #pragma unroll
        for (int mt = 0; mt < 2; mt++)
            afr[mt] = *(const bf16x8*)&Als[(wave * 32 + mt * 16 + lm) * LDP + k0];
        #pragma unroll
        for (int nt = 0; nt < 8; nt++)
            bfr[nt] = *(const bf16x8*)&Bls[(nt * 16 + lm) * LDP + k0];
        #pragma unroll
        for (int mt = 0; mt < 2; mt++)
            #pragma unroll
            for (int nt = 0; nt < 8; nt++)
                acc[mt][nt] = __builtin_amdgcn_mfma_f32_16x16x32_bf16(
                    afr[mt], bfr[nt], acc[mt][nt], 0, 0, 0);
    }
    bf16* kb = kv + ((size_t)b * C2n + oc0) * HWn + px0;
    #pragma unroll
    for (int mt = 0; mt < 2; mt++) {
        int ocl = wave * 32 + mt * 16 + kq * 4;
        #pragma unroll
        for (int nt = 0; nt < 8; nt++) {
            int px = nt * 16 + lm;
            #pragma unroll
            for (int r = 0; r < 4; r++)
                kb[(size_t)(ocl + r) * HWn + px] = f2b(acc[mt][nt][r]);
        }
    }
}

// ---------------- depthwise 3x3 SAME, vectorized via LDS strip ----------------
__global__ void dw_kernel(const bf16* __restrict__ kv,
                          const float* __restrict__ Wdw,
                          bf16* __restrict__ kvdw) {
    __shared__ float st[18][132];
    int tid = threadIdx.x;
    int r0  = blockIdx.x * 16;
    int ch  = blockIdx.y;
    int b   = blockIdx.z;
    float w[9];
    #pragma unroll
    for (int t = 0; t < 9; t++) w[t] = Wdw[ch * 9 + t];
    const bf16* base = kv + ((size_t)b * C2n + ch) * HWn;
    if (tid < 18) { st[tid][0] = 0.f; st[tid][129] = 0.f; }
    for (int i = tid; i < 288; i += 256) {
        int row = i >> 4, sg = (i & 15) << 3;
        int gr = r0 - 1 + row;
        bf16x8 v = {0, 0, 0, 0, 0, 0, 0, 0};
        if (gr >= 0 && gr < Hn) v = *(const bf16x8*)&base[(size_t)gr * Wn + sg];
        #pragma unroll
        for (int j = 0; j < 8; j++) st[row][1 + sg + j] = s2f(v[j]);
    }
    __syncthreads();
    int orow = tid >> 4, sg = (tid & 15) << 3;
    float o[8];
    #pragma unroll
    for (int j = 0; j < 8; j++) o[j] = 0.f;
    #pragma unroll
    for (int dy = 0; dy < 3; dy++)
        #pragma unroll
        for (int dx = 0; dx < 3; dx++) {
            float ww = w[dy * 3 + dx];
            #pragma unroll
            for (int j = 0; j < 8; j++) o[j] += ww * st[orow + dy][sg + j + dx];
        }
    bf16x8 ov;
    #pragma unroll
    for (int j = 0; j < 8; j++) ov[j] = f2bs(o[j]);
    *(bf16x8*)&kvdw[((size_t)b * C2n + ch) * HWn + (size_t)(r0 + orow) * Wn + sg] = ov;
}

// ---------------- q conv 3x3 as implicit GEMM via MFMA ----------------
__global__ __launch_bounds__(256) void qconv_mfma_kernel(
        const bf16* __restrict__ yn_pm,    // [b][px][c]
        const bf16* __restrict__ wq_pk,    // [tap][oc][c]
        bf16* __restrict__ q) {            // [b][oc][px]
    __shared__ short Als[128 * LDP];
    __shared__ short Bls[128 * LDP];
    int tid  = threadIdx.x;
    int y    = blockIdx.x;
    int oc0  = blockIdx.y * 128;
    int b    = blockIdx.z;
    int wave = tid >> 6, lane = tid & 63;
    int lm = lane & 15, kq = lane >> 4;
    int k0 = kq * 8;

    f32x4 acc[2][8];
    #pragma unroll
    for (int mt = 0; mt < 2; mt++)
        #pragma unroll
        for (int nt = 0; nt < 8; nt++) acc[mt][nt] = (f32x4){0.f, 0.f, 0.f, 0.f};

    const short* ypb = (const short*)(yn_pm + (size_t)b * HWn * Cn);

    for (int tap = 0; tap < 9; tap++) {
        int dy = tap / 3 - 1, dx = tap % 3 - 1;
        int yy = y + dy;
        if (yy < 0 || yy >= Hn) continue;
        const short* wtap  = (const short*)(wq_pk + (size_t)tap * Cn * Cn);
        const short* ybase = ypb + (size_t)yy * Wn * Cn;
        for (int kc = 0; kc < Cn; kc += 32) {
            __syncthreads();
            for (int i = tid; i < 512; i += 256) {
                int r = i >> 2, sg = (i & 3) * 8;
                *(bf16x8*)&Als[r * LDP + sg] =
                    *(const bf16x8*)&wtap[(size_t)(oc0 + r) * Cn + kc + sg];
                int xs = r + dx;
                bf16x8 v = {0, 0, 0, 0, 0, 0, 0, 0};
                if (xs >= 0 && xs < Wn)
                    v = *(const bf16x8*)&ybase[(size_t)xs * Cn + kc + sg];
                *(bf16x8*)&Bls[r * LDP + sg] = v;
            }
            __syncthreads();
            bf16x8 afr[2], bfr[8];
            #pragma unroll
            for (int mt = 0; mt < 2; mt++)
                afr[mt] = *(const bf16x8*)&Als[(wave * 32 + mt * 16 + lm) * LDP + k0];
            #pragma unroll
            for (int nt = 0; nt < 8; nt++)
                bfr[nt] = *(const bf16x8*)&Bls[(nt * 16 + lm) * LDP + k0];
            #pragma unroll
            for (int mt = 0; mt < 2; mt++)
                #pragma unroll
                for (int nt = 0; nt < 8; nt++)
                    acc[mt][nt] = __builtin_amdgcn_mfma_f32_16x16x32_bf16(
                        afr[mt], bfr[nt], acc[mt][nt], 0, 0, 0);
        }
    }
    bf16* qb = q + ((size_t)b * Cn + oc0) * HWn + (size_t)y * Wn;
    #pragma unroll
    for (int mt = 0; mt < 2; mt++) {
        int ocl = wave * 32 + mt * 16 + kq * 4;
        #pragma unroll
        for (int nt = 0; nt < 8; nt++) {
            int px = nt * 16 + lm;
            #pragma unroll
            for (int r = 0; r < 4; r++)
                qb[(size_t)(ocl + r) * HWn + px] = f2b(acc[mt][nt][r]);
        }
    }
}

// ---------------- per-row rsqrt(sumsq) scales for q and k ----------------
__global__ void norm_kernel(const bf16* __restrict__ q,
                            const bf16* __restrict__ kvdw,
                            float* __restrict__ qs,
                            float* __restrict__ ks) {
    int row = blockIdx.x;
    int b = row >> 8, c = row & 255;
    int tid = threadIdx.x;
    const bf16* src = (blockIdx.y == 0)
        ? q    + ((size_t)b * Cn  + c) * HWn
        : kvdw + ((size_t)b * C2n + c) * HWn;
    float ssum = 0.f;
    for (int i = tid; i < HWn; i += 256) {
        float v = b2f(src[i]);
        ssum += v * v;
    }
    __shared__ float red[256];
    red[tid] = ssum; __syncthreads();
    if (tid < 128) red[tid] += red[tid + 128];
    __syncthreads();
    if (tid < 64) red[tid] += red[tid + 64];
    __syncthreads();
    if (tid < 32) {
        float v = red[tid] + red[tid + 32];
        for (int off = 16; off > 0; off >>= 1) v += __shfl_xor(v, off);
        if (tid == 0) {
            float* dst = (blockIdx.y == 0) ? qs : ks;
            dst[row] = 1.f / fmaxf(sqrtf(v), 1e-12f);
        }
    }
}

// ---------------- QK^T partials via MFMA: S[c][d] = sum_n q[c][n]k[d][n] ----------------
// grid (8 n-splits, 32 bh); each wave MFMAs the full 32x32 S over its n-sub.
__global__ __launch_bounds__(256) void attn_qk_kernel(
        const bf16* __restrict__ q,        // [b][c][hw]
        const bf16* __restrict__ kvdw,     // [b][2c][hw] (k = first half)
        float* __restrict__ partial) {     // [bh][split][32][32]
    __shared__ short qls[32 * 264];
    __shared__ short kls[32 * 264];
    __shared__ float sred[4][1024];
    int tid   = threadIdx.x;
    int split = blockIdx.x;                // 0..7
    int bh    = blockIdx.y;                // 0..31
    int b = bh >> 3, h = bh & 7;
    int wave = tid >> 6, lane = tid & 63;
    int lm = lane & 15, kq = lane >> 4;

    const short* qbase = (const short*)(q    + ((size_t)(b * Cn  + h * CHn)) * HWn) + split * 2048;
    const short* kbase = (const short*)(kvdw + ((size_t)(b * C2n + h * CHn)) * HWn) + split * 2048;

    f32x4 acc[2][2];
    #pragma unroll
    for (int mt = 0; mt < 2; mt++)
        #pragma unroll
        for (int nt = 0; nt < 2; nt++) acc[mt][nt] = (f32x4){0.f, 0.f, 0.f, 0.f};

    for (int n0 = 0; n0 < 2048; n0 += 256) {
        __syncthreads();
        for (int i = tid; i < 1024; i += 256) {
            int r = i >> 5, sg = (i & 31) * 8;
            *(bf16x8*)&qls[r * 264 + sg] = *(const bf16x8*)&qbase[(size_t)r * HWn + n0 + sg];
            *(bf16x8*)&kls[r * 264 + sg] = *(const bf16x8*)&kbase[(size_t)r * HWn + n0 + sg];
        }
        __syncthreads();
        int nb = wave * 64;
        #pragma unroll
        for (int kk = 0; kk < 64; kk += 32) {
            bf16x8 afr[2], bfr[2];
            #pragma unroll
            for (int mt = 0; mt < 2; mt++)
                afr[mt] = *(const bf16x8*)&qls[(mt * 16 + lm) * 264 + nb + kk + kq * 8];
            #pragma unroll
            for (int nt = 0; nt < 2; nt++)
                bfr[nt] = *(const bf16x8*)&kls[(nt * 16 + lm) * 264 + nb + kk + kq * 8];
            #pragma unroll
            for (int mt = 0; mt < 2; mt++)
                #pragma unroll
                for (int nt = 0; nt < 2; nt++)
                    acc[mt][nt] = __builtin_amdgcn_mfma_f32_16x16x32_bf16(
                        afr[mt], bfr[nt], acc[mt][nt], 0, 0, 0);
        }
    }
    __syncthreads();
    #pragma unroll
    for (int mt = 0; mt < 2; mt++)
        #pragma unroll
        for (int nt = 0; nt < 2; nt++)
            #pragma unroll
            for (int r = 0; r < 4; r++) {
                int c = mt * 16 + kq * 4 + r;
                int d = nt * 16 + lm;
                sred[wave][c * 32 + d] = acc[mt][nt][r];
            }
    __syncthreads();
    float* pb = partial + ((size_t)bh * 8 + split) * 1024;
    for (int i = tid; i < 1024; i += 256)
        pb[i] = sred[0][i] + sred[1][i] + sred[2][i] + sred[3][i];
}

// ---------------- reduce partials, scale, softmax ----------------
__global__ void attn_softmax_kernel(const float* __restrict__ partial,
                                    const float* __restrict__ qs,
                                    const float* __restrict__ ks,
                                    const float* __restrict__ temp,
                                    float* __restrict__ attn) {
    __shared__ float S[1024];
    int bh = blockIdx.x;
    int b = bh >> 3, h = bh & 7;
    int tid = threadIdx.x;
    for (int i = tid; i < 1024; i += 256) {
        float v = 0.f;
        #pragma unroll
        for (int sp = 0; sp < 8; sp++)
            v += partial[((size_t)bh * 8 + sp) * 1024 + i];
        int c = i >> 5, d = i & 31;
        v *= qs[b * Cn + h * CHn + c] * ks[b * Cn + h * CHn + d] * temp[h];
        S[i] = v;
    }
    __syncthreads();
    if (tid < 32) {
        int c = tid;
        float m = -1e30f;
        for (int d = 0; d < 32; d++) m = fmaxf(m, S[c * 32 + d]);
        float sum = 0.f;
        for (int d = 0; d < 32; d++) sum += __expf(S[c * 32 + d] - m);
        float inv = 1.f / sum;
        for (int d = 0; d < 32; d++)
            attn[(size_t)bh * 1024 + c * 32 + d] = __expf(S[c * 32 + d] - m) * inv;
    }
}

// ---------------- out = attn @ v  (writes PIXEL-MAJOR) ----------------
__global__ void av_kernel(const float* __restrict__ attn,
                          const bf16* __restrict__ kvdw,
                          bf16* __restrict__ ao_pm) {
    int bh = blockIdx.y;
    int b = bh >> 3, h = bh & 7;
    int tid = threadIdx.x;
    int n = blockIdx.x * 256 + tid;
    __shared__ float At[32][32];
    for (int i = tid; i < 1024; i += 256) {
        int cc = i >> 5, dd = i & 31;
        At[dd][cc] = attn[((size_t)bh * 32 + cc) * 32 + dd];
    }
    __syncthreads();
    const bf16* vbase = kvdw + ((size_t)b * C2n + Cn + h * CHn) * HWn;
    float acc[32];
    #pragma unroll
    for (int c = 0; c < 32; c++) acc[c] = 0.f;
    for (int d = 0; d < 32; d++) {
        float vv = b2f(vbase[(size_t)d * HWn + n]);
        #pragma unroll
        for (int c = 0; c < 32; c++) acc[c] += At[d][c] * vv;
    }
    bf16* obase = ao_pm + ((size_t)b * HWn + n) * Cn + h * CHn;
    #pragma unroll
    for (int g = 0; g < 4; g++) {
        bf16x8 v;
        #pragma unroll
        for (int j = 0; j < 8; j++) v[j] = f2bs(acc[g * 8 + j]);
        *(bf16x8*)&obase[g * 8] = v;
    }
}

// ---------------- proj 1x1 via MFMA + residual (writes final f32) ----------------
__global__ __launch_bounds__(256) void proj_mfma_kernel(
        const bf16* __restrict__ ao_pm,    // [b][px][c]
        const bf16* __restrict__ wpr_pk,   // [oc][c] bf16 (256x256)
        const bf16* __restrict__ yn_pm,    // [b][px][c] (residual)
        float* __restrict__ out) {         // [b][oc][px] f32
    __shared__ short Als[128 * LDP];
    __shared__ short Bls[128 * LDP];
    int tid  = threadIdx.x;
    int px0  = blockIdx.x * 128;
    int oc0  = blockIdx.y * 128;
    int b    = blockIdx.z;
    int wave = tid >> 6, lane = tid & 63;
    int lm = lane & 15, kq = lane >> 4;
    int k0 = kq * 8;

    f32x4 acc[2][8];
    #pragma unroll
    for (int mt = 0; mt < 2; mt++)
        #pragma unroll
        for (int nt = 0; nt < 8; nt++) acc[mt][nt] = (f32x4){0.f, 0.f, 0.f, 0.f};

    const short* ab = (const short*)(ao_pm + ((size_t)b * HWn + px0) * Cn);
    const short* wb = (const short*)wpr_pk + (size_t)oc0 * Cn;

    for (int kc = 0; kc < Cn; kc += 32) {
        __syncthreads();
        for (int i = tid; i < 512; i += 256) {
            int r = i >> 2, sg = (i & 3) * 8;
            *(bf16x8*)&Als[r * LDP + sg] = *(const bf16x8*)&wb[(size_t)r * Cn + kc + sg];
            *(bf16x8*)&Bls[r * LDP + sg] = *(const bf16x8*)&ab[(size_t)r * Cn + kc + sg];
        }
        __syncthreads();
        bf16x8 afr[2], bfr[8];
        #pragma unroll
        for (int mt = 0; mt < 2; mt++)
            afr[mt] = *(const bf16x8*)&Als[(wave * 32 + mt * 16 + lm) * LDP + k0];
        #pragma unroll
        for (int nt = 0; nt < 8; nt++)
            bfr[nt] = *(const bf16x8*)&Bls[(nt * 16 + lm) * LDP + k0];
        #pragma unroll
        for (int mt = 0; mt < 2; mt++)
            #pragma unroll
            for (int nt = 0; nt < 8; nt++)
                acc[mt][nt] = __builtin_amdgcn_mfma_f32_16x16x32_bf16(
                    afr[mt], bfr[nt], acc[mt][nt], 0, 0, 0);
    }
    const bf16* ynb = yn_pm + ((size_t)b * HWn + px0) * Cn;
    float* ob = out + ((size_t)b * Cn + oc0) * HWn + px0;
    #pragma unroll
    for (int mt = 0; mt < 2; mt++) {
        int ocl = wave * 32 + mt * 16 + kq * 4;
        #pragma unroll
        for (int nt = 0; nt < 8; nt++) {
            int px = nt * 16 + lm;
            #pragma unroll
            for (int r = 0; r < 4; r++)
                ob[(size_t)(ocl + r) * HWn + px] =
                    acc[mt][nt][r] + b2f(ynb[(size_t)px * Cn + oc0 + ocl + r]);
        }
    }
}

extern "C" void kernel_launch(void* const* d_in, const int* in_sizes, int n_in,
                              void* d_out, int out_size, void* d_ws, size_t ws_size,
                              hipStream_t stream) {
    const float* x     = (const float*)d_in[0];
    const float* y     = (const float*)d_in[1];
    const float* lnkw  = (const float*)d_in[2];
    const float* lnkb  = (const float*)d_in[3];
    const float* lnqw  = (const float*)d_in[4];
    const float* lnqb  = (const float*)d_in[5];
    const float* Wkv   = (const float*)d_in[6];
    const float* Wdw   = (const float*)d_in[7];
    const float* Wq    = (const float*)d_in[8];
    const float* Wproj = (const float*)d_in[9];
    const float* temp  = (const float*)d_in[10];
    float* out = (float*)d_out;

    char* ws = (char*)d_ws;
    const size_t TEN = (size_t)Bn * Cn * HWn;          // 16,777,216 elems
    // R0 [0, 64 MiB): xn_cm | yn_cm  ->  kv  ->  q_cm
    bf16* xn_cm = (bf16*)ws;
    bf16* yn_cm = (bf16*)(ws + TEN * 2);
    bf16* kv    = (bf16*)ws;
    bf16* q_cm  = (bf16*)ws;
    // R1 [64, 128 MiB): kvdw
    bf16* kvdw  = (bf16*)(ws + TEN * 4);
    // R2 [128, 160 MiB): xn_pm -> ao_pm
    bf16* xn_pm = (bf16*)(ws + TEN * 8);
    bf16* ao_pm = xn_pm;
    // R3 [160, 192 MiB): yn_pm (lives until proj residual)
    bf16* yn_pm = (bf16*)(ws + TEN * 10);
    // small buffers
    char* wp = ws + TEN * 12;
    bf16* wq_pk  = (bf16*)wp;  wp += 589824 * 2;
    bf16* wkv_pk = (bf16*)wp;  wp += 131072 * 2;
    bf16* wpr_pk = (bf16*)wp;  wp += 65536 * 2;
    float* qs    = (float*)wp; wp += 4096;
    float* ksr   = (float*)wp; wp += 4096;
    float* attnP = (float*)wp; wp += 131072;
    float* partS = (float*)wp; wp += 1048576;   // [32 bh][8 splits][32][32] f32

    // 0. weight preprocessing
    wq_repack_kernel<<<dim3(256), 256, 0, stream>>>(Wq, wq_pk);
    cast_kernel<<<dim3(128), 256, 0, stream>>>(Wkv, wkv_pk, C2n * Cn);
    cast_kernel<<<dim3(64), 256, 0, stream>>>(Wproj, wpr_pk, Cn * Cn);
    // 1-2. LayerNorms (channel-major bf16)
    ln_kernel<<<dim3(Bn * HWn / 256), 256, 0, stream>>>(x, lnkw, lnkb, xn_cm);
    ln_kernel<<<dim3(Bn * HWn / 256), 256, 0, stream>>>(y, lnqw, lnqb, yn_cm);
    // 3-4. transposes to pixel-major
    transpose_kernel<<<dim3(HWn / 64, Cn / 64, Bn), 256, 0, stream>>>(xn_cm, xn_pm);
    transpose_kernel<<<dim3(HWn / 64, Cn / 64, Bn), 256, 0, stream>>>(yn_cm, yn_pm);
    // 5. kv = 1x1 conv via MFMA (overwrites xn_cm/yn_cm region — both dead)
    kv1x1_mfma_kernel<<<dim3(HWn / 128, C2n / 128, Bn), 256, 0, stream>>>(xn_pm, wkv_pk, kv);
    // 6. depthwise 3x3 -> kvdw
    dw_kernel<<<dim3(Hn / 16, C2n, Bn), 256, 0, stream>>>(kv, Wdw, kvdw);
    // 7. q = 3x3 conv via MFMA -> q_cm (kv dead after dw)
    qconv_mfma_kernel<<<dim3(Hn, Cn / 128, Bn), 256, 0, stream>>>(yn_pm, wq_pk, q_cm);
    // 8. L2-norm scales
    norm_kernel<<<dim3(Bn * Cn, 2), 256, 0, stream>>>(q_cm, kvdw, qs, ksr);
    // 9a. QK^T partials via MFMA
    attn_qk_kernel<<<dim3(8, Bn * HEADSn), 256, 0, stream>>>(q_cm, kvdw, partS);
    // 9b. reduce + scale + softmax
    attn_softmax_kernel<<<dim3(Bn * HEADSn), 256, 0, stream>>>(partS, qs, ksr, temp, attnP);
    // 10. attn @ v -> ao_pm (xn_pm dead after kv1x1)
    av_kernel<<<dim3(HWn / 256, Bn * HEADSn), 256, 0, stream>>>(attnP, kvdw, ao_pm);
    // 11. proj 1x1 via MFMA + residual -> final f32 output
    proj_mfma_kernel<<<dim3(HWn / 128, Cn / 128, Bn), 256, 0, stream>>>(ao_pm, wpr_pk, yn_pm, out);
}